// Round 8
// baseline (183.360 us; speedup 1.0000x reference)
//
#include <hip/hip_runtime.h>

#define VOCAB 50257
#define NTOK 4096
#define P1_THREADS 256
#define P2_THREADS 1024
#define NEG_HUGE -3.402823466e+38f

typedef float floatx4 __attribute__((ext_vector_type(4)));

// Online softmax state over a multiset:
//   m  = max, m2 = second max, Z = sum e^{x-m}, S1 = sum (x-m) e^{x-m}
struct OS { float m, m2, Z, S1; };

__device__ __forceinline__ void os_init(OS& s) {
  s.m = NEG_HUGE; s.m2 = NEG_HUGE; s.Z = 0.0f; s.S1 = 0.0f;
}

// Merge a local summary (ml, m2l, zl, s1l) into state a. One exp total.
__device__ __forceinline__ void os_merge(OS& a, float ml, float m2l, float zl, float s1l) {
  float M  = fmaxf(a.m, ml);
  float mn = fminf(a.m, ml);
  float m2 = fmaxf(fmaxf(a.m2, m2l), mn);
  float e  = __expf(mn - M);          // exp of the smaller-max shift; other side is e^0=1
  bool  om = a.m >= ml;
  float eo = om ? 1.0f : e;
  float en = om ? e : 1.0f;
  float S1 = eo * fmaf(a.m - M, a.Z, a.S1) + en * fmaf(ml - M, zl, s1l);
  float Z  = fmaf(eo, a.Z, en * zl);
  a.m = M; a.m2 = m2; a.Z = Z; a.S1 = S1;
}

// Batched update with 4 elements: local max/2nd-max/Z/S1, then one merge.
__device__ __forceinline__ void os_update4(OS& s, floatx4 v) {
  float a  = fmaxf(v.x, v.y), b = fminf(v.x, v.y);
  float c  = fmaxf(v.z, v.w), d = fminf(v.z, v.w);
  float ml  = fmaxf(a, c);
  float m2l = fmaxf(fminf(a, c), fmaxf(b, d));    // exact 2nd max of 4
  float d0 = v.x - ml, d1 = v.y - ml, d2 = v.z - ml, d3 = v.w - ml;
  float e0 = __expf(d0), e1 = __expf(d1), e2 = __expf(d2), e3 = __expf(d3);
  float zl  = (e0 + e1) + (e2 + e3);
  float s1l = fmaf(d0, e0, fmaf(d1, e1, fmaf(d2, e2, d3 * e3)));
  os_merge(s, ml, m2l, zl, s1l);
}

// min 8 waves/EU with 256-thread blocks => 8 blocks/CU => caps VGPR at 64,
// doubling resident waves vs the unconstrained allocation.
__global__ __launch_bounds__(P1_THREADS, 8) void cggr_rowstats(
    const float* __restrict__ logits, const int* __restrict__ targets,
    float* __restrict__ diff, float* __restrict__ loss, float* __restrict__ conf)
{
  const int row = blockIdx.x;
  const float* __restrict__ x = logits + (size_t)row * VOCAB;
  const int tid = threadIdx.x;

  float xt = 0.0f;
  if (tid == 0) xt = x[targets[row]];

  // row base offset mod 4 == row mod 4 (VOCAB % 4 == 1): peel head for 16B alignment
  const int head = (4 - (row & 3)) & 3;
  const int nv4  = (VOCAB - head) >> 2;
  const floatx4* __restrict__ x4 = (const floatx4*)(x + head);

  OS s0, s1, s2, s3;
  os_init(s0); os_init(s1); os_init(s2); os_init(s3);

  // 4 independent streams: 4 outstanding 16B nontemporal loads per thread per iteration
  int i = tid;
  for (; i + 3 * P1_THREADS < nv4; i += 4 * P1_THREADS) {
    floatx4 va = __builtin_nontemporal_load(&x4[i]);
    floatx4 vb = __builtin_nontemporal_load(&x4[i +     P1_THREADS]);
    floatx4 vc = __builtin_nontemporal_load(&x4[i + 2 * P1_THREADS]);
    floatx4 vd = __builtin_nontemporal_load(&x4[i + 3 * P1_THREADS]);
    os_update4(s0, va);
    os_update4(s1, vb);
    os_update4(s2, vc);
    os_update4(s3, vd);
  }
  for (; i < nv4; i += P1_THREADS)
    os_update4(s0, __builtin_nontemporal_load(&x4[i]));

  if (tid < head) os_merge(s1, x[tid], NEG_HUGE, 1.0f, 0.0f);
  for (int t = head + 4 * nv4 + tid; t < VOCAB; t += P1_THREADS)
    os_merge(s1, x[t], NEG_HUGE, 1.0f, 0.0f);

  os_merge(s0, s1.m, s1.m2, s1.Z, s1.S1);
  os_merge(s2, s3.m, s3.m2, s3.Z, s3.S1);
  os_merge(s0, s2.m, s2.m2, s2.Z, s2.S1);

  // wave64 butterfly
  for (int m = 1; m < 64; m <<= 1) {
    OS o;
    o.m  = __shfl_xor(s0.m,  m);
    o.m2 = __shfl_xor(s0.m2, m);
    o.Z  = __shfl_xor(s0.Z,  m);
    o.S1 = __shfl_xor(s0.S1, m);
    os_merge(s0, o.m, o.m2, o.Z, o.S1);
  }

  __shared__ OS sred[P1_THREADS / 64];
  const int lane = tid & 63, wid = tid >> 6;
  if (lane == 0) sred[wid] = s0;
  __syncthreads();

  if (tid == 0) {
    OS a = sred[0];
    for (int w = 1; w < P1_THREADS / 64; ++w)
      os_merge(a, sred[w].m, sred[w].m2, sred[w].Z, sred[w].S1);
    float m       = a.m;
    float lnZ     = logf(a.Z);
    float ptl     = m + lnZ - xt;            // -log_softmax[target]
    float entropy = lnZ - a.S1 / a.Z;
    float log_v   = logf((float)VOCAB);
    float cf      = 1.0f / a.Z;              // p_max
    float margin  = (1.0f - __expf(a.m2 - m)) / a.Z;
    float dif     = (entropy / log_v + (1.0f - margin) + ptl / log_v) / 3.0f;
    diff[row] = dif;
    loss[row] = ptl;
    conf[row] = cf;
  }
}

__global__ __launch_bounds__(P2_THREADS) void cggr_finalize(
    const float* __restrict__ diff, const float* __restrict__ loss,
    const float* __restrict__ conf, const int* __restrict__ step_ptr,
    float* __restrict__ out)
{
  __shared__ float redF[16];
  __shared__ int   redI[2][16];
  __shared__ float redL[16], redC[16];

  const int tid = threadIdx.x, lane = tid & 63, wid = tid >> 6;

  // Each thread owns 4 rows (strided, coalesced), kept in registers.
  unsigned u[4];
  float cs = 0.0f;
  #pragma unroll
  for (int j = 0; j < 4; ++j) {
    int i = tid + P2_THREADS * j;
    cs += conf[i];
    unsigned b = __float_as_uint(diff[i]);
    u[j] = b ^ ((b & 0x80000000u) ? 0xFFFFFFFFu : 0x80000000u);  // monotonic map
  }

  // ---- mean confidence -> k (computed redundantly by all threads) ----
  for (int m = 1; m < 64; m <<= 1) cs += __shfl_xor(cs, m);
  if (lane == 0) redF[wid] = cs;
  __syncthreads();
  float sum = 0.0f;
  #pragma unroll
  for (int w = 0; w < 16; ++w) sum += redF[w];
  float mean_conf  = sum / (float)NTOK;
  float step       = (float)step_ptr[0];
  float progress   = fminf(1.0f, step / 1000.0f);       // WARMUP_STEPS
  float base_ratio = 1.0f - progress * (1.0f - 0.25f);  // MIN_TOKENS_RATIO
  float ratio      = base_ratio * (1.0f + 0.5f * (0.5f - mean_conf));
  ratio = fminf(fmaxf(ratio, 0.05f), 1.0f);
  int k = (int)rintf(ratio * (float)NTOK);              // round-half-even = jnp.round
  k = k < 1 ? 1 : (k > NTOK ? NTOK : k);

  // ---- k-th largest via MSB binary search on monotonic keys ----
  // Difficulties are strictly positive => key top bit always set => 31 rounds.
  unsigned T = 0x80000000u;
  int parity = 0;
  for (int bit = 30; bit >= 0; --bit) {
    unsigned cand = T | (1u << bit);
    int cnt = (u[0] >= cand) + (u[1] >= cand) + (u[2] >= cand) + (u[3] >= cand);
    for (int m = 1; m < 64; m <<= 1) cnt += __shfl_xor(cnt, m);
    if (lane == 0) redI[parity][wid] = cnt;
    __syncthreads();
    int tot = 0;
    #pragma unroll
    for (int w = 0; w < 16; ++w) tot += redI[parity][w];
    if (tot >= k) T = cand;       // all threads take identical branch
    parity ^= 1;
  }
  // key compare == float compare (strict monotonic bijection): mask directly on keys

  float ls = 0.0f, cn = 0.0f;
  #pragma unroll
  for (int j = 0; j < 4; ++j) {
    if (u[j] >= T) { ls += loss[tid + P2_THREADS * j]; cn += 1.0f; }
  }
  for (int m = 1; m < 64; m <<= 1) {
    ls += __shfl_xor(ls, m);
    cn += __shfl_xor(cn, m);
  }
  if (lane == 0) { redL[wid] = ls; redC[wid] = cn; }
  __syncthreads();
  if (tid == 0) {
    float tl = 0.0f, tc = 0.0f;
    #pragma unroll
    for (int w = 0; w < 16; ++w) { tl += redL[w]; tc += redC[w]; }
    out[0] = tl / fmaxf(tc, 1.0f);
  }
}

extern "C" void kernel_launch(void* const* d_in, const int* in_sizes, int n_in,
                              void* d_out, int out_size, void* d_ws, size_t ws_size,
                              hipStream_t stream) {
  const float* logits  = (const float*)d_in[0];
  const int*   targets = (const int*)d_in[1];
  const int*   step    = (const int*)d_in[2];
  float* ws   = (float*)d_ws;
  float* diff = ws;
  float* loss = ws + NTOK;
  float* conf = ws + 2 * NTOK;

  hipLaunchKernelGGL(cggr_rowstats, dim3(NTOK), dim3(P1_THREADS), 0, stream,
                     logits, targets, diff, loss, conf);
  hipLaunchKernelGGL(cggr_finalize, dim3(1), dim3(P2_THREADS), 0, stream,
                     diff, loss, conf, step, (float*)d_out);
}

// Round 9
// 154.249 us; speedup vs baseline: 1.1887x; 1.1887x over previous
//
#include <hip/hip_runtime.h>

#define VOCAB 50257
#define NTOK 4096
#define P1_THREADS 256
#define P2_THREADS 1024
#define NEG_HUGE -3.402823466e+38f

typedef float floatx4 __attribute__((ext_vector_type(4)));

// Online softmax state over a multiset:
//   m  = max, m2 = second max, Z = sum e^{x-m}, S1 = sum (x-m) e^{x-m}
struct OS { float m, m2, Z, S1; };

__device__ __forceinline__ void os_init(OS& s) {
  s.m = NEG_HUGE; s.m2 = NEG_HUGE; s.Z = 0.0f; s.S1 = 0.0f;
}

// Merge a local summary (ml, m2l, zl, s1l) into state a. One exp total.
__device__ __forceinline__ void os_merge(OS& a, float ml, float m2l, float zl, float s1l) {
  float M  = fmaxf(a.m, ml);
  float mn = fminf(a.m, ml);
  float m2 = fmaxf(fmaxf(a.m2, m2l), mn);
  float e  = __expf(mn - M);          // exp of the smaller-max shift; other side is e^0=1
  bool  om = a.m >= ml;
  float eo = om ? 1.0f : e;
  float en = om ? e : 1.0f;
  float S1 = eo * fmaf(a.m - M, a.Z, a.S1) + en * fmaf(ml - M, zl, s1l);
  float Z  = fmaf(eo, a.Z, en * zl);
  a.m = M; a.m2 = m2; a.Z = Z; a.S1 = S1;
}

// Batched update with 4 elements: local max/2nd-max/Z/S1, then one merge.
__device__ __forceinline__ void os_update4(OS& s, floatx4 v) {
  float a  = fmaxf(v.x, v.y), b = fminf(v.x, v.y);
  float c  = fmaxf(v.z, v.w), d = fminf(v.z, v.w);
  float ml  = fmaxf(a, c);
  float m2l = fmaxf(fminf(a, c), fmaxf(b, d));    // exact 2nd max of 4
  float d0 = v.x - ml, d1 = v.y - ml, d2 = v.z - ml, d3 = v.w - ml;
  float e0 = __expf(d0), e1 = __expf(d1), e2 = __expf(d2), e3 = __expf(d3);
  float zl  = (e0 + e1) + (e2 + e3);
  float s1l = fmaf(d0, e0, fmaf(d1, e1, fmaf(d2, e2, d3 * e3)));
  os_merge(s, ml, m2l, zl, s1l);
}

// NOTE: no min-waves launch_bounds — R8 showed forcing 64 VGPR spills (183 µs).
__global__ __launch_bounds__(P1_THREADS) void cggr_rowstats(
    const float* __restrict__ logits, const int* __restrict__ targets,
    float* __restrict__ diff, float* __restrict__ loss, float* __restrict__ conf)
{
  const int row = blockIdx.x;
  const float* __restrict__ x = logits + (size_t)row * VOCAB;
  const int tid = threadIdx.x;

  float xt = 0.0f;
  if (tid == 0) xt = x[targets[row]];

  // row base offset mod 4 == row mod 4 (VOCAB % 4 == 1): peel head for 16B alignment
  const int head = (4 - (row & 3)) & 3;
  const int nv4  = (VOCAB - head) >> 2;
  const floatx4* __restrict__ x4 = (const floatx4*)(x + head);

  OS s0, s1, s2, s3;
  os_init(s0); os_init(s1); os_init(s2); os_init(s3);

  // 4 independent streams: 4 outstanding 16B nontemporal loads per thread per
  // iteration. nt = +14 µs (R7 A/B); depth beyond 4 neutral (R5).
  int i = tid;
  for (; i + 3 * P1_THREADS < nv4; i += 4 * P1_THREADS) {
    floatx4 va = __builtin_nontemporal_load(&x4[i]);
    floatx4 vb = __builtin_nontemporal_load(&x4[i +     P1_THREADS]);
    floatx4 vc = __builtin_nontemporal_load(&x4[i + 2 * P1_THREADS]);
    floatx4 vd = __builtin_nontemporal_load(&x4[i + 3 * P1_THREADS]);
    os_update4(s0, va);
    os_update4(s1, vb);
    os_update4(s2, vc);
    os_update4(s3, vd);
  }
  for (; i < nv4; i += P1_THREADS)
    os_update4(s0, __builtin_nontemporal_load(&x4[i]));

  if (tid < head) os_merge(s1, x[tid], NEG_HUGE, 1.0f, 0.0f);
  for (int t = head + 4 * nv4 + tid; t < VOCAB; t += P1_THREADS)
    os_merge(s1, x[t], NEG_HUGE, 1.0f, 0.0f);

  os_merge(s0, s1.m, s1.m2, s1.Z, s1.S1);
  os_merge(s2, s3.m, s3.m2, s3.Z, s3.S1);
  os_merge(s0, s2.m, s2.m2, s2.Z, s2.S1);

  // wave64 butterfly
  for (int m = 1; m < 64; m <<= 1) {
    OS o;
    o.m  = __shfl_xor(s0.m,  m);
    o.m2 = __shfl_xor(s0.m2, m);
    o.Z  = __shfl_xor(s0.Z,  m);
    o.S1 = __shfl_xor(s0.S1, m);
    os_merge(s0, o.m, o.m2, o.Z, o.S1);
  }

  __shared__ OS sred[P1_THREADS / 64];
  const int lane = tid & 63, wid = tid >> 6;
  if (lane == 0) sred[wid] = s0;
  __syncthreads();

  if (tid == 0) {
    OS a = sred[0];
    for (int w = 1; w < P1_THREADS / 64; ++w)
      os_merge(a, sred[w].m, sred[w].m2, sred[w].Z, sred[w].S1);
    float m       = a.m;
    float lnZ     = logf(a.Z);
    float ptl     = m + lnZ - xt;            // -log_softmax[target]
    float entropy = lnZ - a.S1 / a.Z;
    float log_v   = logf((float)VOCAB);
    float cf      = 1.0f / a.Z;              // p_max
    float margin  = (1.0f - __expf(a.m2 - m)) / a.Z;
    float dif     = (entropy / log_v + (1.0f - margin) + ptl / log_v) / 3.0f;
    diff[row] = dif;
    loss[row] = ptl;
    conf[row] = cf;
  }
}

__global__ __launch_bounds__(P2_THREADS) void cggr_finalize(
    const float* __restrict__ diff, const float* __restrict__ loss,
    const float* __restrict__ conf, const int* __restrict__ step_ptr,
    float* __restrict__ out)
{
  __shared__ float redF[16];
  __shared__ int   redI[2][16];
  __shared__ float redL[16], redC[16];

  const int tid = threadIdx.x, lane = tid & 63, wid = tid >> 6;

  // Each thread owns 4 rows (strided, coalesced), kept in registers.
  unsigned u[4];
  float cs = 0.0f;
  #pragma unroll
  for (int j = 0; j < 4; ++j) {
    int i = tid + P2_THREADS * j;
    cs += conf[i];
    unsigned b = __float_as_uint(diff[i]);
    u[j] = b ^ ((b & 0x80000000u) ? 0xFFFFFFFFu : 0x80000000u);  // monotonic map
  }

  // ---- mean confidence -> k (computed redundantly by all threads) ----
  for (int m = 1; m < 64; m <<= 1) cs += __shfl_xor(cs, m);
  if (lane == 0) redF[wid] = cs;
  __syncthreads();
  float sum = 0.0f;
  #pragma unroll
  for (int w = 0; w < 16; ++w) sum += redF[w];
  float mean_conf  = sum / (float)NTOK;
  float step       = (float)step_ptr[0];
  float progress   = fminf(1.0f, step / 1000.0f);       // WARMUP_STEPS
  float base_ratio = 1.0f - progress * (1.0f - 0.25f);  // MIN_TOKENS_RATIO
  float ratio      = base_ratio * (1.0f + 0.5f * (0.5f - mean_conf));
  ratio = fminf(fmaxf(ratio, 0.05f), 1.0f);
  int k = (int)rintf(ratio * (float)NTOK);              // round-half-even = jnp.round
  k = k < 1 ? 1 : (k > NTOK ? NTOK : k);

  // ---- k-th largest via MSB binary search on monotonic keys ----
  // Difficulties are strictly positive => key top bit always set => 31 rounds.
  unsigned T = 0x80000000u;
  int parity = 0;
  for (int bit = 30; bit >= 0; --bit) {
    unsigned cand = T | (1u << bit);
    int cnt = (u[0] >= cand) + (u[1] >= cand) + (u[2] >= cand) + (u[3] >= cand);
    for (int m = 1; m < 64; m <<= 1) cnt += __shfl_xor(cnt, m);
    if (lane == 0) redI[parity][wid] = cnt;
    __syncthreads();
    int tot = 0;
    #pragma unroll
    for (int w = 0; w < 16; ++w) tot += redI[parity][w];
    if (tot >= k) T = cand;       // all threads take identical branch
    parity ^= 1;
  }
  // key compare == float compare (strict monotonic bijection): mask directly on keys

  float ls = 0.0f, cn = 0.0f;
  #pragma unroll
  for (int j = 0; j < 4; ++j) {
    if (u[j] >= T) { ls += loss[tid + P2_THREADS * j]; cn += 1.0f; }
  }
  for (int m = 1; m < 64; m <<= 1) {
    ls += __shfl_xor(ls, m);
    cn += __shfl_xor(cn, m);
  }
  if (lane == 0) { redL[wid] = ls; redC[wid] = cn; }
  __syncthreads();
  if (tid == 0) {
    float tl = 0.0f, tc = 0.0f;
    #pragma unroll
    for (int w = 0; w < 16; ++w) { tl += redL[w]; tc += redC[w]; }
    out[0] = tl / fmaxf(tc, 1.0f);
  }
}

extern "C" void kernel_launch(void* const* d_in, const int* in_sizes, int n_in,
                              void* d_out, int out_size, void* d_ws, size_t ws_size,
                              hipStream_t stream) {
  const float* logits  = (const float*)d_in[0];
  const int*   targets = (const int*)d_in[1];
  const int*   step    = (const int*)d_in[2];
  float* ws   = (float*)d_ws;
  float* diff = ws;
  float* loss = ws + NTOK;
  float* conf = ws + 2 * NTOK;

  hipLaunchKernelGGL(cggr_rowstats, dim3(NTOK), dim3(P1_THREADS), 0, stream,
                     logits, targets, diff, loss, conf);
  hipLaunchKernelGGL(cggr_finalize, dim3(1), dim3(P2_THREADS), 0, stream,
                     diff, loss, conf, step, (float*)d_out);
}